// Round 2
// baseline (234.168 us; speedup 1.0000x reference)
//
#include <hip/hip_runtime.h>

#define NB    64
#define IN    512
#define OUT   512
#define NTOK  512      // B*T
#define K     2
#define NSEL  (NTOK*K) // 1024
#define NCHUNK 8
#define IC    (IN/NCHUNK)   // 64 rows per chunk
#define TCAP  32            // token capacity per pass
#define TLOC  16            // tokens per token-group

// Pass 1: build CSR lists of selection-indices per bank. Single block.
__global__ __launch_bounds__(1024) void build_lists(const int* __restrict__ sel,
                                                    int* __restrict__ counts,
                                                    int* __restrict__ offsets,
                                                    int* __restrict__ list) {
    __shared__ int lcnt[NB];
    __shared__ int loff[NB];
    const int t = threadIdx.x;
    if (t < NB) lcnt[t] = 0;
    __syncthreads();
    const int bank = sel[t];
    atomicAdd(&lcnt[bank], 1);
    __syncthreads();
    if (t == 0) {
        int run = 0;
        for (int b = 0; b < NB; ++b) { loff[b] = run; run += lcnt[b]; }
    }
    __syncthreads();
    if (t < NB) { counts[t] = lcnt[t]; offsets[t] = loff[t]; lcnt[t] = 0; }
    __syncthreads();
    const int pos = loff[bank] + atomicAdd(&lcnt[bank], 1);
    list[pos] = t;
}

// Pass 2: one block per (bank, IN-chunk). 512 threads:
//   tg = t>>8 (2 token groups of 16), rg = (t>>7)&1 (2 row groups of 32 rows),
//   ct = t&127 -> float4 of columns (128*4 = 512 cols, perfectly coalesced).
// Weight tile [64 rows][512 cols] streamed once; xs staged in LDS pre-scaled
// by prob; partial outputs atomically added into out.
__global__ __launch_bounds__(512) void banked_gemv(
    const float* __restrict__ x,      // [NTOK][IN]
    const float* __restrict__ probs,  // [NSEL]
    const float* __restrict__ W,      // [NB][IN][OUT]
    const float* __restrict__ bias,   // [NB][OUT]
    const int* __restrict__ counts,
    const int* __restrict__ offsets,
    const int* __restrict__ list,
    float* __restrict__ out)          // [NTOK][OUT]
{
    __shared__ float xs[TCAP][IC];    // 8 KB
    __shared__ int   tok_s[TCAP];
    __shared__ float prob_s[TCAP];

    const int bank   = blockIdx.x >> 3;
    const int ichunk = blockIdx.x & (NCHUNK - 1);
    const int n      = counts[bank];
    if (n == 0) return;
    const int start = offsets[bank];
    const int i0    = ichunk * IC;

    const int t    = threadIdx.x;
    const int ct   = t & 127;
    const int rg   = (t >> 7) & 1;    // row group: rows rg*32 .. rg*32+31
    const int tg   = t >> 8;          // token group: tokens tg*16 .. tg*16+15
    const int col4 = ct * 4;

    const float* wrow = W + (size_t)bank * IN * OUT + (size_t)(i0 + rg * 32) * OUT + col4;
    float4 bias_v = make_float4(0.f, 0.f, 0.f, 0.f);
    if (ichunk == 0) bias_v = *reinterpret_cast<const float4*>(bias + bank * OUT + col4);

    for (int c0 = 0; c0 < n; c0 += TCAP) {
        // stage token ids + probs
        if (t < TCAP) {
            const int idx = c0 + t;
            const int e = (idx < n) ? list[start + idx] : -1;
            tok_s[t]  = (e >= 0) ? (e >> 1) : 0;
            prob_s[t] = (e >= 0) ? probs[e] : 0.0f;
        }
        __syncthreads();
        // stage x chunk, pre-scaled: 32 rows x 16 float4 = 512 loads, 1/thread
        {
            const int row = t >> 4;        // 0..31
            const int c4  = t & 15;        // 0..15
            float4 v = reinterpret_cast<const float4*>(x + (size_t)tok_s[row] * IN + i0)[c4];
            const float p = prob_s[row];
            v.x *= p; v.y *= p; v.z *= p; v.w *= p;
            reinterpret_cast<float4*>(&xs[row][0])[c4] = v;
        }
        __syncthreads();

        float4 acc[TLOC];
        #pragma unroll
        for (int j = 0; j < TLOC; ++j) acc[j] = make_float4(0.f, 0.f, 0.f, 0.f);

        #pragma unroll
        for (int r4 = 0; r4 < 32; r4 += 4) {
            float4 w0 = *reinterpret_cast<const float4*>(wrow + (size_t)(r4 + 0) * OUT);
            float4 w1 = *reinterpret_cast<const float4*>(wrow + (size_t)(r4 + 1) * OUT);
            float4 w2 = *reinterpret_cast<const float4*>(wrow + (size_t)(r4 + 2) * OUT);
            float4 w3 = *reinterpret_cast<const float4*>(wrow + (size_t)(r4 + 3) * OUT);
            #pragma unroll
            for (int j = 0; j < TLOC; ++j) {
                const float4 xv = *reinterpret_cast<const float4*>(&xs[tg * TLOC + j][rg * 32 + r4]);
                acc[j].x += xv.x * w0.x + xv.y * w1.x + xv.z * w2.x + xv.w * w3.x;
                acc[j].y += xv.x * w0.y + xv.y * w1.y + xv.z * w2.y + xv.w * w3.y;
                acc[j].z += xv.x * w0.z + xv.y * w1.z + xv.z * w2.z + xv.w * w3.z;
                acc[j].w += xv.x * w0.w + xv.y * w1.w + xv.z * w2.w + xv.w * w3.w;
            }
        }

        #pragma unroll
        for (int j = 0; j < TLOC; ++j) {
            const int slot = tg * TLOC + j;
            if (c0 + slot < n) {
                float* o = out + (size_t)tok_s[slot] * OUT + col4;
                const float p = prob_s[slot];
                atomicAdd(o + 0, acc[j].x + p * bias_v.x);
                atomicAdd(o + 1, acc[j].y + p * bias_v.y);
                atomicAdd(o + 2, acc[j].z + p * bias_v.z);
                atomicAdd(o + 3, acc[j].w + p * bias_v.w);
            }
        }
        __syncthreads();
    }
}

extern "C" void kernel_launch(void* const* d_in, const int* in_sizes, int n_in,
                              void* d_out, int out_size, void* d_ws, size_t ws_size,
                              hipStream_t stream) {
    const float* x     = (const float*)d_in[0];
    const int*   sel   = (const int*)d_in[1];
    const float* probs = (const float*)d_in[2];
    const float* W     = (const float*)d_in[3];
    const float* bias  = (const float*)d_in[4];
    float* out = (float*)d_out;

    int* counts  = (int*)d_ws;        // 64
    int* offsets = counts + NB;       // 64
    int* list    = offsets + NB;      // 1024

    hipMemsetAsync(d_out, 0, (size_t)out_size * sizeof(float), stream);
    build_lists<<<1, NSEL, 0, stream>>>(sel, counts, offsets, list);
    banked_gemv<<<NB * NCHUNK, 512, 0, stream>>>(x, probs, W, bias, counts, offsets, list, out);
}

// Round 3
// 39.395 us; speedup vs baseline: 5.9441x; 5.9441x over previous
//
#include <hip/hip_runtime.h>

#define NB    64
#define IN    512
#define OUT   512
#define NTOK  512       // B*T
#define K     2
#define NSEL  (NTOK*K)  // 1024
#define NTILE 8         // col tiles of 64
#define CW    (OUT/NTILE)   // 64 cols per tile
#define TCAP  32        // tokens per pass
#define TLOC  16        // tokens per token-group (2 groups)
#define NRW   8         // row slices

// Pass 1: CSR lists of selection-indices per bank. Single block.
__global__ __launch_bounds__(1024) void build_lists(const int* __restrict__ sel,
                                                    int* __restrict__ counts,
                                                    int* __restrict__ offsets,
                                                    int* __restrict__ list) {
    __shared__ int lcnt[NB];
    __shared__ int loff[NB];
    const int t = threadIdx.x;
    if (t < NB) lcnt[t] = 0;
    __syncthreads();
    const int bank = sel[t];
    atomicAdd(&lcnt[bank], 1);
    __syncthreads();
    if (t == 0) {
        int run = 0;
        for (int b = 0; b < NB; ++b) { loff[b] = run; run += lcnt[b]; }
    }
    __syncthreads();
    if (t < NB) { counts[t] = lcnt[t]; offsets[t] = loff[t]; lcnt[t] = 0; }
    __syncthreads();
    const int pos = loff[bank] + atomicAdd(&lcnt[bank], 1);
    list[pos] = t;
}

// Pass 2: block = (bank, 64-col tile). 256 threads:
//   ct = t&15   -> float4 column (16*4 = 64 cols)
//   g  = (t>>4)&1 -> token group (16 tokens each)
//   rw = t>>5   -> row slice: float4-row-blocks r4 == rw (mod 8)
// Each weight element fetched once per block (g-duplicates coalesce in-wave).
// Partials over rw reduced through LDS (reusing the xs staging buffer).
// Results stored per-selection into ysel (no atomics).
__global__ __launch_bounds__(256) void banked_gemv(
    const float* __restrict__ x,      // [NTOK][IN]
    const float* __restrict__ probs,  // [NSEL]
    const float* __restrict__ W,      // [NB][IN][OUT]
    const float* __restrict__ bias,   // [NB][OUT]
    const int* __restrict__ counts,
    const int* __restrict__ offsets,
    const int* __restrict__ list,
    float* __restrict__ ysel)         // [NSEL][OUT]
{
    // union: xs = 32 tokens x 512 floats (64 KB); red = 32 x 130 float4 (65 KB)
    __shared__ __align__(16) char ldsraw[32 * 130 * 16];
    float*  xs  = (float*)ldsraw;
    float4* red = (float4*)ldsraw;
    __shared__ int   tok_s[TCAP];
    __shared__ float prob_s[TCAP];

    const int bank = blockIdx.x >> 3;
    const int tile = blockIdx.x & (NTILE - 1);
    const int n    = counts[bank];
    if (n == 0) return;
    const int start = offsets[bank];
    const int col0  = tile * CW;

    const int t  = threadIdx.x;
    const int ct = t & 15;
    const int g  = (t >> 4) & 1;
    const int rw = t >> 5;

    const float* wbase = W + (size_t)bank * IN * OUT + col0 + ct * 4;

    for (int c0 = 0; c0 < n; c0 += TCAP) {
        if (t < TCAP) {
            const int idx = c0 + t;
            const int e = (idx < n) ? list[start + idx] : -1;
            tok_s[t]  = (e >= 0) ? (e >> 1) : 0;
            prob_s[t] = (e >= 0) ? probs[e] : 0.0f;
        }
        __syncthreads();

        // stage xs pre-scaled: 32 rows x 128 float4 = 4096; 16 per thread
        #pragma unroll
        for (int k = 0; k < 16; ++k) {
            const int oid = t + k * 256;
            const int row = oid >> 7;
            const int c4  = oid & 127;
            float4 v = reinterpret_cast<const float4*>(x + (size_t)tok_s[row] * IN)[c4];
            const float p = prob_s[row];
            v.x *= p; v.y *= p; v.z *= p; v.w *= p;
            reinterpret_cast<float4*>(xs + row * IN)[c4] = v;
        }
        __syncthreads();

        float4 acc[TLOC];
        #pragma unroll
        for (int j = 0; j < TLOC; ++j) acc[j] = make_float4(0.f, 0.f, 0.f, 0.f);

        #pragma unroll 4
        for (int k = 0; k < 16; ++k) {
            const int R = 4 * (rw + 8 * k);    // rows R..R+3
            const float* wr = wbase + (size_t)R * OUT;
            const float4 w0 = *reinterpret_cast<const float4*>(wr);
            const float4 w1 = *reinterpret_cast<const float4*>(wr + OUT);
            const float4 w2 = *reinterpret_cast<const float4*>(wr + 2 * OUT);
            const float4 w3 = *reinterpret_cast<const float4*>(wr + 3 * OUT);
            #pragma unroll
            for (int j = 0; j < TLOC; ++j) {
                const int s = g * TLOC + j;
                const float4 xv = *reinterpret_cast<const float4*>(xs + s * IN + R);
                acc[j].x += xv.x * w0.x + xv.y * w1.x + xv.z * w2.x + xv.w * w3.x;
                acc[j].y += xv.x * w0.y + xv.y * w1.y + xv.z * w2.y + xv.w * w3.y;
                acc[j].z += xv.x * w0.z + xv.y * w1.z + xv.z * w2.z + xv.w * w3.z;
                acc[j].w += xv.x * w0.w + xv.y * w1.w + xv.z * w2.w + xv.w * w3.w;
            }
        }
        __syncthreads();   // all xs reads done; safe to reuse LDS as red

        #pragma unroll
        for (int j = 0; j < TLOC; ++j) {
            const int s = g * TLOC + j;
            red[s * 130 + rw * 16 + ct] = acc[j];
        }
        __syncthreads();

        // output: 32 tokens x 16 float4-cols = 512 outputs; 2 per thread
        #pragma unroll
        for (int k = 0; k < 2; ++k) {
            const int oid = t + k * 256;
            const int s = oid >> 4;
            const int c = oid & 15;
            if (c0 + s < n) {
                float4 sum = make_float4(0.f, 0.f, 0.f, 0.f);
                #pragma unroll
                for (int r = 0; r < NRW; ++r) {
                    const float4 v = red[s * 130 + r * 16 + c];
                    sum.x += v.x; sum.y += v.y; sum.z += v.z; sum.w += v.w;
                }
                const float p = prob_s[s];
                const float4 bv = *reinterpret_cast<const float4*>(bias + bank * OUT + col0 + c * 4);
                sum.x += p * bv.x; sum.y += p * bv.y; sum.z += p * bv.z; sum.w += p * bv.w;
                const int e = list[start + c0 + s];
                *reinterpret_cast<float4*>(ysel + (size_t)e * OUT + col0 + c * 4) = sum;
            }
        }
        __syncthreads();   // before restaging xs in next pass
    }
}

// Pass 3: out[t] = ysel[2t] + ysel[2t+1]
__global__ __launch_bounds__(256) void combine(const float* __restrict__ ysel,
                                               float* __restrict__ out) {
    const int i  = blockIdx.x * 256 + threadIdx.x;   // float4 index, 65536 total
    const int tk = i >> 7;          // token
    const int c  = i & 127;         // float4 col
    const float4* y4 = reinterpret_cast<const float4*>(ysel);
    const float4 a = y4[(size_t)tk * 256 + c];
    const float4 b = y4[(size_t)tk * 256 + 128 + c];
    float4 r;
    r.x = a.x + b.x; r.y = a.y + b.y; r.z = a.z + b.z; r.w = a.w + b.w;
    reinterpret_cast<float4*>(out)[i] = r;
}

extern "C" void kernel_launch(void* const* d_in, const int* in_sizes, int n_in,
                              void* d_out, int out_size, void* d_ws, size_t ws_size,
                              hipStream_t stream) {
    const float* x     = (const float*)d_in[0];
    const int*   sel   = (const int*)d_in[1];
    const float* probs = (const float*)d_in[2];
    const float* W     = (const float*)d_in[3];
    const float* bias  = (const float*)d_in[4];
    float* out = (float*)d_out;

    int* counts  = (int*)d_ws;        // 64
    int* offsets = counts + NB;       // 64
    int* list    = offsets + NB;      // 1024
    float* ysel  = (float*)((char*)d_ws + 4608);   // [NSEL][OUT] = 2 MB, 16B-aligned

    build_lists<<<1, NSEL, 0, stream>>>(sel, counts, offsets, list);
    banked_gemv<<<NB * NTILE, 256, 0, stream>>>(x, probs, W, bias, counts, offsets, list, ysel);
    combine<<<(NTOK * OUT / 4) / 256, 256, 0, stream>>>(ysel, out);
}